// Round 3
// baseline (83.598 us; speedup 1.0000x reference)
//
#include <hip/hip_runtime.h>

// Cutout: out[b,c,y,x] = img[b,c,y,x] * keep(b,y,x)
// B=64, C=3, H=512, W=512, MAX_HOLES=5 (num_holes in [0,5))
// Memory-roofline kernel: each thread moves 8 consecutive pixels x 3 channels
// (96 B) with non-temporal float4 access (pure stream, no reuse).

#define BB 64
#define CC 3
#define HH 512
#define WW 512
#define KK 5
#define W4 (WW / 4)              // 128 float4 per row
#define W8 (WW / 8)              // 64 8-pixel groups per row
#define PLANE4 (HH * W4)         // 65536 float4 per (b,c) plane

typedef float v4f __attribute__((ext_vector_type(4)));

__global__ __launch_bounds__(256) void cutout_kernel(
    const v4f* __restrict__ img,
    const int* __restrict__ num_holes,
    const int* __restrict__ ys,
    const int* __restrict__ xs,
    const int* __restrict__ hs,
    const int* __restrict__ ws,
    v4f* __restrict__ out)
{
    int idx = blockIdx.x * blockDim.x + threadIdx.x;
    // total threads = B * H * W8 = 64 * 512 * 64 = 2097152 (exact grid)

    int b   = idx >> 15;          // / (H*W8) = / 32768
    int rem = idx & 32767;
    int y   = rem >> 6;           // / W8
    int x8  = rem & 63;           // 8-pixel group within row
    int x0  = x8 << 3;            // first pixel x of this group

    int n = num_holes[b];         // wave-uniform (whole wave shares b)

    float m[8];
#pragma unroll
    for (int j = 0; j < 8; ++j) m[j] = 1.0f;

    for (int k = 0; k < n; ++k) { // n <= 4, wave-uniform loop
        int yc = ys[b * KK + k];
        int xc = xs[b * KK + k];
        int hh = hs[b * KK + k];
        int wv = ws[b * KK + k];
        int y1 = max(0, yc - hh / 2);
        int y2 = min(HH, yc + hh / 2);
        if (y >= y1 && y < y2) {
            int x1 = max(0, xc - wv / 2);
            int x2 = min(WW, xc + wv / 2);
#pragma unroll
            for (int j = 0; j < 8; ++j) {
                int xx = x0 + j;
                if (xx >= x1 && xx < x2) m[j] = 0.0f;
            }
        }
    }

    // base float4 index for (b, c=0, y, x8*2)
    size_t p = (size_t)b * (CC * PLANE4) + (size_t)y * W4 + (size_t)(x8 << 1);
#pragma unroll
    for (int c = 0; c < CC; ++c) {
        size_t q = p + (size_t)c * PLANE4;
        v4f a = __builtin_nontemporal_load(&img[q]);
        v4f d = __builtin_nontemporal_load(&img[q + 1]);
        a.x *= m[0]; a.y *= m[1]; a.z *= m[2]; a.w *= m[3];
        d.x *= m[4]; d.y *= m[5]; d.z *= m[6]; d.w *= m[7];
        __builtin_nontemporal_store(a, &out[q]);
        __builtin_nontemporal_store(d, &out[q + 1]);
    }
}

extern "C" void kernel_launch(void* const* d_in, const int* in_sizes, int n_in,
                              void* d_out, int out_size, void* d_ws, size_t ws_size,
                              hipStream_t stream) {
    const v4f* img         = (const v4f*)d_in[0];
    const int* num_holes   = (const int*)d_in[1];
    const int* ys          = (const int*)d_in[2];
    const int* xs          = (const int*)d_in[3];
    const int* hs          = (const int*)d_in[4];
    const int* ws          = (const int*)d_in[5];
    v4f* out               = (v4f*)d_out;

    int total = BB * HH * W8;           // 2097152 threads, exact
    int block = 256;
    int grid  = total / block;          // 8192 blocks
    cutout_kernel<<<grid, block, 0, stream>>>(img, num_holes, ys, xs, hs, ws, out);
}

// Round 4
// 73.065 us; speedup vs baseline: 1.1442x; 1.1442x over previous
//
#include <hip/hip_runtime.h>

// Cutout: out[b,c,y,x] = img[b,c,y,x] * keep(b,y,x)
// B=64, C=3, H=512, W=512, MAX_HOLES=5 (num_holes in [0,5))
//
// R3: exact d2d-copy memory shape — one thread per float4, lane-contiguous,
// plain loads/stores. 2D grid: blockIdx.y = plane (b*3+c) so b is uniform
// and hole params are scalar loads; mask math is a handful of VALU ops.

#define BB 64
#define CC 3
#define HH 512
#define WW 512
#define KK 5
#define W4 (WW / 4)              // 128 float4 per row
#define PLANE4 (HH * W4)         // 65536 float4 per (b,c) plane

typedef float v4f __attribute__((ext_vector_type(4)));

__global__ __launch_bounds__(256) void cutout_kernel(
    const v4f* __restrict__ img,
    const int* __restrict__ num_holes,
    const int* __restrict__ ys,
    const int* __restrict__ xs,
    const int* __restrict__ hs,
    const int* __restrict__ ws,
    v4f* __restrict__ out)
{
    int plane = blockIdx.y;                       // b*3 + c, 0..191 (uniform)
    int b     = plane / 3;                        // uniform scalar divide
    int pos   = blockIdx.x * 256 + threadIdx.x;   // 0..65535 within plane
    int y     = pos >> 7;                         // row
    int x0    = (pos & 127) << 2;                 // first pixel x of quad

    float m0 = 1.0f, m1 = 1.0f, m2 = 1.0f, m3 = 1.0f;

    int n = num_holes[b];                         // scalar load, uniform
    for (int k = 0; k < n; ++k) {                 // uniform loop, n <= 4
        int yc = ys[b * KK + k];
        int xc = xs[b * KK + k];
        int hh = hs[b * KK + k];
        int wv = ws[b * KK + k];
        int y1 = max(0, yc - hh / 2);
        int y2 = min(HH, yc + hh / 2);
        int x1 = max(0, xc - wv / 2);
        int x2 = min(WW, xc + wv / 2);
        bool iny = (y >= y1) & (y < y2);
        if (iny) {
            if ((x0 + 0) >= x1 && (x0 + 0) < x2) m0 = 0.0f;
            if ((x0 + 1) >= x1 && (x0 + 1) < x2) m1 = 0.0f;
            if ((x0 + 2) >= x1 && (x0 + 2) < x2) m2 = 0.0f;
            if ((x0 + 3) >= x1 && (x0 + 3) < x2) m3 = 0.0f;
        }
    }

    size_t q = (size_t)plane * PLANE4 + (size_t)pos;
    v4f v = img[q];
    v.x *= m0; v.y *= m1; v.z *= m2; v.w *= m3;
    out[q] = v;
}

extern "C" void kernel_launch(void* const* d_in, const int* in_sizes, int n_in,
                              void* d_out, int out_size, void* d_ws, size_t ws_size,
                              hipStream_t stream) {
    const v4f* img         = (const v4f*)d_in[0];
    const int* num_holes   = (const int*)d_in[1];
    const int* ys          = (const int*)d_in[2];
    const int* xs          = (const int*)d_in[3];
    const int* hs          = (const int*)d_in[4];
    const int* ws          = (const int*)d_in[5];
    v4f* out               = (v4f*)d_out;

    dim3 grid(PLANE4 / 256, BB * CC);   // (256, 192) blocks of 256 threads
    cutout_kernel<<<grid, dim3(256), 0, stream>>>(img, num_holes, ys, xs, hs, ws, out);
}